// Round 3
// baseline (10954.121 us; speedup 1.0000x reference)
//
#include <hip/hip_runtime.h>
#include <hip/hip_bf16.h>

typedef unsigned int u32;

__device__ __forceinline__ float sigf(float x){ return 1.0f/(1.0f + __expf(-x)); }

// DPP row_shr:N add (reduction toward lane 0 of each 8-lane group, VALU pipe)
template<int CTRL>
__device__ __forceinline__ float dpp_shr_add(float v){
  int s = __builtin_amdgcn_mov_dpp(__float_as_int(v), CTRL, 0xf, 0xf, true);
  return v + __int_as_float(s);
}

// ---------------------------------------------------------------------------
// ws layout (float offsets)
// ---------------------------------------------------------------------------
#define GI_OFF   0
#define GI_SZ    (2560*768)
#define HF_OFF   (GI_OFF + GI_SZ)
#define HF_SZ    (1280*256)
#define HB_OFF   (HF_OFF + HF_SZ)
#define X1_OFF   (HB_OFF + HF_SZ)
#define X1_SZ    (128*30*30)
#define X2_OFF   (X1_OFF + X1_SZ)
#define X2_SZ    (64*14*14)
#define XIMG_OFF (X2_OFF + X2_SZ)
#define XIMG_SZ  (64*6*6)
#define AKIN_OFF (XIMG_OFF + XIMG_SZ)
#define PSUM_OFF (AKIN_OFF + 768)
#define NSUM_OFF (PSUM_OFF + 512)

// ---------------- gi precompute: gi[row][768] = emb[tok] @ wih[j].T + bih[j] ----
__global__ __launch_bounds__(256) void gi_kernel(
    const float* __restrict__ emb, const float* __restrict__ wih_all,
    const float* __restrict__ bih_all,
    const int* __restrict__ prev, const int* __restrict__ curr, const int* __restrict__ nxt,
    float* __restrict__ gi_all)
{
  const int offs[7] = {0,512,768,1280,1792,2048,2560};
  int row0 = blockIdx.x * 16;
  int j = 0;
  while (row0 >= offs[j+1]) ++j;
  int t0 = row0 - offs[j];
  int sel = j % 3;
  const int* inst = (sel==0)? prev : (sel==1)? curr : nxt;

  __shared__ __align__(16) float e[16][32];
  int u = threadIdx.x;
  for (int idx=u; idx<512; idx+=256){
    int r = idx >> 5, k = idx & 31;
    e[r][k] = emb[(size_t)inst[t0+r]*32 + k];
  }
  __syncthreads();

  const float* wih = wih_all + (size_t)j*768*32;
  const float* bih = bih_all + (size_t)j*768;
  for (int g3=0; g3<3; ++g3){
    int o = g3*256 + u;
    float bb = bih[o];
    float acc[16];
#pragma unroll
    for (int r=0;r<16;++r) acc[r]=bb;
    const float* wr = wih + (size_t)o*32;
#pragma unroll
    for (int k=0;k<32;++k){
      float w = wr[k];
#pragma unroll
      for (int r=0;r<16;++r) acc[r] += w * e[r][k];
    }
    for (int r=0;r<16;++r) gi_all[(size_t)(row0+r)*768 + o] = acc[r];
  }
}

// ---------------- GRU sequential scan: 6 blocks, one per GRU -------------------
// 1024 threads: thread = (row-group rg = u>>3 -> 6 rows, k-eighth kq = u&7 -> 32 k).
// Per-thread weights: 6 rows x 32 k = 192 f32 = 48 float4 (register-resident).
__global__ __launch_bounds__(1024,1) void gru_scan_kernel(
    const float* __restrict__ whh_all, const float* __restrict__ bhh_all,
    const float* __restrict__ gi_all, float* __restrict__ hf, float* __restrict__ hb)
{
  const int lens[6] = {512,256,512,512,256,512};
  const int offs[6] = {0,512,768,1280,1792,2048};
  int j = blockIdx.x;
  int u = threadIdx.x;
  int len = lens[j];
  const float* gi = gi_all + (size_t)offs[j]*768;
  float* outp = ((j<3)? hf : hb) + (size_t)offs[j%3]*256;

  int kq = u & 7;      // k-eighth [0,8): k range kq*32 .. kq*32+31
  int rg = u >> 3;     // row group [0,128)
  int r0 = rg * 6;     // rows r0 .. r0+5

  // Weights, rotation-swizzled to match the LDS read pattern:
  //   wreg[rr][i] = whh[j][r0+rr][ kq*32 + ((i+kq)&7)*4 .. +4 ]
  float4 wreg[6][8];
#pragma unroll
  for (int rr=0; rr<6; ++rr){
    const float4* wp = (const float4*)(whh_all + ((size_t)j*768 + (r0+rr))*256 + kq*32);
#pragma unroll
    for (int i=0;i<8;++i) wreg[rr][i] = wp[(i+kq)&7];
  }
  float bhv[6];
#pragma unroll
  for (int rr=0; rr<6; ++rr) bhv[rr] = bhh_all[j*768 + r0 + rr];

  __shared__ __align__(16) float hsh[256];
  __shared__ float gacc[768];
  if (u < 256) hsh[u] = 0.0f;
  __syncthreads();

  const float4* hsh4 = (const float4*)hsh;
  // rotated LDS float4 indices (loop-invariant, live in registers)
  int hidx[8];
#pragma unroll
  for (int i=0;i<8;++i) hidx[i] = kq*8 + ((i+kq)&7);

  for (int t=0; t<len; ++t){
    // issue gi loads early; consumed after the barrier (hides L2 latency)
    float gr=0.f, gz=0.f, gn=0.f;
    if (u < 256){
      const float* git = gi + (size_t)t*768;
      gr = git[u]; gz = git[256+u]; gn = git[512+u];
    }
    // partial dots: 6 rows x 32 k  (bank-conflict-free rotated reads)
    float a0=0.f,a1=0.f,a2=0.f,a3=0.f,a4=0.f,a5=0.f;
#pragma unroll
    for (int i=0;i<8;++i){
      float4 hv = hsh4[hidx[i]];
      float4 w;
      w = wreg[0][i]; a0 += w.x*hv.x + w.y*hv.y + w.z*hv.z + w.w*hv.w;
      w = wreg[1][i]; a1 += w.x*hv.x + w.y*hv.y + w.z*hv.z + w.w*hv.w;
      w = wreg[2][i]; a2 += w.x*hv.x + w.y*hv.y + w.z*hv.z + w.w*hv.w;
      w = wreg[3][i]; a3 += w.x*hv.x + w.y*hv.y + w.z*hv.z + w.w*hv.w;
      w = wreg[4][i]; a4 += w.x*hv.x + w.y*hv.y + w.z*hv.z + w.w*hv.w;
      w = wreg[5][i]; a5 += w.x*hv.x + w.y*hv.y + w.z*hv.z + w.w*hv.w;
    }
    // reduce across the 8 k-lanes (DPP, VALU pipe; lane kq==0 holds the sum)
    a0 = dpp_shr_add<0x114>(dpp_shr_add<0x112>(dpp_shr_add<0x111>(a0)));
    a1 = dpp_shr_add<0x114>(dpp_shr_add<0x112>(dpp_shr_add<0x111>(a1)));
    a2 = dpp_shr_add<0x114>(dpp_shr_add<0x112>(dpp_shr_add<0x111>(a2)));
    a3 = dpp_shr_add<0x114>(dpp_shr_add<0x112>(dpp_shr_add<0x111>(a3)));
    a4 = dpp_shr_add<0x114>(dpp_shr_add<0x112>(dpp_shr_add<0x111>(a4)));
    a5 = dpp_shr_add<0x114>(dpp_shr_add<0x112>(dpp_shr_add<0x111>(a5)));
    if (kq == 0){
      gacc[r0+0] = bhv[0] + a0;
      gacc[r0+1] = bhv[1] + a1;
      gacc[r0+2] = bhv[2] + a2;
      gacc[r0+3] = bhv[3] + a3;
      gacc[r0+4] = bhv[4] + a4;
      gacc[r0+5] = bhv[5] + a5;
    }
    __syncthreads();
    if (u < 256){
      float r  = sigf(gr + gacc[u]);
      float z  = sigf(gz + gacc[256+u]);
      float n  = tanhf(gn + r*gacc[512+u]);
      float h2 = (1.0f - z)*n + z*hsh[u];
      outp[(size_t)t*256 + u] = h2;
      hsh[u] = h2;
    }
    __syncthreads();
  }
}

// ---------------- convs (direct, one thread per output) ------------------------
__global__ __launch_bounds__(256) void conv1_kernel(
    const float* __restrict__ x, const float* __restrict__ w, const float* __restrict__ b,
    float* __restrict__ y)
{
  int idx = blockIdx.x*256 + threadIdx.x;
  if (idx >= 128*30*30) return;
  int c = idx/900, rem = idx%900, i = rem/30, jx = rem%30;
  float acc = b[c];
  const float* wc = w + (size_t)c*3*8*8;
  for (int ic=0; ic<3; ++ic)
    for (int ky=0; ky<8; ++ky){
      const float* xrow = x + ((size_t)ic*124 + (i*4+ky))*124 + jx*4;
      const float* wrow = wc + (ic*8+ky)*8;
#pragma unroll
      for (int kx=0; kx<8; ++kx) acc += xrow[kx] * wrow[kx];
    }
  y[idx] = fmaxf(acc, 0.0f);
}

__global__ __launch_bounds__(256) void conv2_kernel(
    const float* __restrict__ x1, const float* __restrict__ w, const float* __restrict__ b,
    float* __restrict__ y)
{
  int idx = blockIdx.x*256 + threadIdx.x;
  if (idx >= 64*14*14) return;
  int c = idx/196, rem = idx%196, i = rem/14, jx = rem%14;
  float acc = b[c];
  for (int ic=0; ic<128; ++ic){
    const float* xc = x1 + (size_t)ic*900;
    const float* wc = w + ((size_t)c*128 + ic)*16;
#pragma unroll
    for (int ky=0; ky<4; ++ky)
#pragma unroll
      for (int kx=0; kx<4; ++kx)
        acc += xc[(i*2+ky)*30 + (jx*2+kx)] * wc[ky*4+kx];
  }
  y[idx] = fmaxf(acc, 0.0f);
}

__global__ __launch_bounds__(256) void conv3_kernel(
    const float* __restrict__ x2, const float* __restrict__ w, const float* __restrict__ b,
    float* __restrict__ y)
{
  int idx = blockIdx.x*256 + threadIdx.x;
  if (idx >= 64*6*6) return;
  int c = idx/36, rem = idx%36, i = rem/6, jx = rem%6;
  float acc = b[c];
  for (int ic=0; ic<64; ++ic){
    const float* xc = x2 + (size_t)ic*196;
    const float* wc = w + ((size_t)c*64 + ic)*16;
#pragma unroll
    for (int ky=0; ky<4; ++ky)
#pragma unroll
      for (int kx=0; kx<4; ++kx)
        acc += xc[(i*2+ky)*14 + (jx*2+kx)] * wc[ky*4+kx];
  }
  y[idx] = fmaxf(acc, 0.0f);
}

// ---------------- image embedding + ak_in assembly -----------------------------
__global__ __launch_bounds__(256) void imgemb_kernel(
    const float* __restrict__ x_img, const float* __restrict__ img_w, const float* __restrict__ img_b,
    const float* __restrict__ hf, const float* __restrict__ hb, float* __restrict__ ak_in)
{
  __shared__ __align__(16) float xs[2304];
  int u = threadIdx.x;
  for (int i=u; i<2304; i+=256) xs[i] = x_img[i];
  __syncthreads();
  float a0=0.f,a1=0.f,a2=0.f,a3=0.f;
  const float4* wr = (const float4*)(img_w + (size_t)u*2304);
  const float4* xv = (const float4*)xs;
  for (int k=0; k<576; ++k){
    float4 w = wr[k], xx = xv[k];
    a0 += w.x*xx.x; a1 += w.y*xx.y; a2 += w.z*xx.z; a3 += w.w*xx.w;
  }
  ak_in[512+u] = img_b[u] + ((a0+a1)+(a2+a3)); // image_emb
  ak_in[u]     = hf[(size_t)767*256+u];        // curr_rep fwd half
  ak_in[256+u] = hb[(size_t)767*256+u];        // curr_rep bwd half (rb[P])
}

// ---------------- attention (block 0 = prev, block 1 = next) -------------------
__global__ __launch_bounds__(512) void attend_kernel(
    const float* __restrict__ ak_in_g,
    const float* __restrict__ akp_w, const float* __restrict__ akp_b,
    const float* __restrict__ akn_w, const float* __restrict__ akn_b,
    const float* __restrict__ bil_p_w, const float* __restrict__ bil_p_b,
    const float* __restrict__ bil_n_w, const float* __restrict__ bil_n_b,
    const float* __restrict__ hf, const float* __restrict__ hb,
    float* __restrict__ prev_sum, float* __restrict__ next_sum)
{
  int blk = blockIdx.x;
  const float* akw = blk? akn_w : akp_w;
  const float* akb = blk? akn_b : akp_b;
  const float* bw  = blk? bil_n_w : bil_p_w;
  float bb         = blk? bil_n_b[0] : bil_p_b[0];
  float* outp      = blk? next_sum : prev_sum;

  int u = threadIdx.x;
  __shared__ __align__(16) float ak[768];
  __shared__ __align__(16) float kk[256];
  __shared__ __align__(16) float q[512];
  __shared__ float s[512], red[512];

  for (int i=u; i<768; i+=512) ak[i] = ak_in_g[i];
  __syncthreads();

  if (u < 256){
    float a0=0.f,a1=0.f,a2=0.f,a3=0.f;
    const float4* wr = (const float4*)(akw + (size_t)u*768);
    const float4* av = (const float4*)ak;
    for (int m=0; m<192; ++m){
      float4 w = wr[m], aa = av[m];
      a0 += w.x*aa.x; a1 += w.y*aa.y; a2 += w.z*aa.z; a3 += w.w*aa.w;
    }
    kk[u] = akb[u] + ((a0+a1)+(a2+a3));
  }
  __syncthreads();

  { // q = k @ bw[0]   (coalesced: lane u reads column u)
    float acc = 0.0f;
    for (int m=0; m<256; ++m) acc += kk[m]*bw[(size_t)m*512 + u];
    q[u] = acc;
  }
  __syncthreads();

  { // scores: s[i] = q . rep[i] + bb
    int i = u;
    const float4* repf = (const float4*)(hf + (size_t)(blk? (768+i) : i)*256);
    const float4* repb = (const float4*)(hb + (size_t)(blk? (511-i) : (1279-i))*256);
    const float4* qf = (const float4*)q;
    float a0=0.f,a1=0.f;
    for (int v=0; v<64; ++v){
      float4 qq = qf[v],  rr = repf[v];
      a0 += qq.x*rr.x + qq.y*rr.y + qq.z*rr.z + qq.w*rr.w;
      float4 q2 = qf[64+v], r2 = repb[v];
      a1 += q2.x*r2.x + q2.y*r2.y + q2.z*r2.z + q2.w*r2.w;
    }
    s[u] = bb + a0 + a1;
  }
  __syncthreads();

  // softmax over 512
  red[u] = s[u]; __syncthreads();
  for (int st=256; st>0; st>>=1){ if (u<st) red[u]=fmaxf(red[u],red[u+st]); __syncthreads(); }
  float mx = red[0]; __syncthreads();
  float ex = __expf(s[u]-mx);
  red[u] = ex; __syncthreads();
  for (int st=256; st>0; st>>=1){ if (u<st) red[u]+=red[u+st]; __syncthreads(); }
  float inv = 1.0f/red[0]; __syncthreads();
  s[u] = ex*inv;
  __syncthreads();

  // weighted sum over rows (coalesced: lane reads column u)
  float o = 0.0f;
  if (u < 256){
    for (int r=0; r<512; ++r){
      const float* rf = hf + (size_t)(blk? (768+r) : r)*256;
      o += s[r]*rf[u];
    }
    outp[u] = o;
  } else {
    int v = u-256;
    for (int r=0; r<512; ++r){
      const float* rb = hb + (size_t)(blk? (511-r) : (1279-r))*256;
      o += s[r]*rb[v];
    }
    outp[u] = o;
  }
}

// ---------------- head: pred/nred, gate, lin, LSTM, outputs --------------------
__global__ __launch_bounds__(1024) void head_kernel(
    const float* __restrict__ prev_sum_g, const float* __restrict__ next_sum_g,
    const float* __restrict__ ak_in_g, const float* __restrict__ x_img,
    const float* __restrict__ pred_w, const float* __restrict__ pred_b,
    const float* __restrict__ nred_w, const float* __restrict__ nred_b,
    const float* __restrict__ gate_w, const float* __restrict__ gate_b,
    const float* __restrict__ lin_w,  const float* __restrict__ lin_b,
    const float* __restrict__ lstm_wih, const float* __restrict__ lstm_whh,
    const float* __restrict__ lstm_bih, const float* __restrict__ lstm_bhh,
    const float* __restrict__ hx, const float* __restrict__ cx,
    const int* __restrict__ tx, const float* __restrict__ time_emb,
    const float* __restrict__ crit_w, const float* __restrict__ crit_b,
    const float* __restrict__ act_w,  const float* __restrict__ act_b,
    float* __restrict__ out)
{
  int u = threadIdx.x;
  __shared__ __align__(16) float ps[512];
  __shared__ __align__(16) float ns[512];
  __shared__ __align__(16) float cr[512];
  __shared__ float pg[64], ng[64], gate[64];
  __shared__ __align__(16) float xg[2304];
  __shared__ __align__(16) float feat[256];
  __shared__ __align__(16) float hxs[256];
  __shared__ float g[1024], cxs[256], z[288];

  if (u < 512){ ps[u]=prev_sum_g[u]; ns[u]=next_sum_g[u]; cr[u]=ak_in_g[u]; }
  if (u >= 512 && u < 768){ int t=u-512; hxs[t]=hx[t]; cxs[t]=cx[t]; }
  for (int i=u; i<2304; i+=1024) xg[i] = x_img[i];
  __syncthreads();

  if (u < 64){
    float a = pred_b[u];
    const float* wr = pred_w + (size_t)u*512;
    for (int k=0;k<512;++k) a += ps[k]*wr[k];
    pg[u] = a;
  } else if (u < 128){
    int t = u-64;
    float a = nred_b[t];
    const float* wr = nred_w + (size_t)t*512;
    for (int k=0;k<512;++k) a += ns[k]*wr[k];
    ng[t] = a;
  }
  __syncthreads();

  if (u < 64){
    float a = gate_b[u];
    const float* wr = gate_w + (size_t)u*640;
    for (int k=0;k<512;++k) a += cr[k]*wr[k];
    for (int k=0;k<64;++k)  a += pg[k]*wr[512+k];
    for (int k=0;k<64;++k)  a += ng[k]*wr[576+k];
    gate[u] = sigf(a);
  }
  __syncthreads();

  for (int i=u; i<2304; i+=1024) xg[i] *= gate[i/36];
  __syncthreads();

  if (u < 256){
    float a0=0.f,a1=0.f,a2=0.f,a3=0.f;
    const float4* wr = (const float4*)(lin_w + (size_t)u*2304);
    const float4* xv = (const float4*)xg;
    for (int k=0;k<576;++k){
      float4 w = wr[k], xx = xv[k];
      a0 += w.x*xx.x; a1 += w.y*xx.y; a2 += w.z*xx.z; a3 += w.w*xx.w;
    }
    feat[u] = fmaxf(lin_b[u] + ((a0+a1)+(a2+a3)), 0.0f);
  }
  __syncthreads();

  {
    float a0=0.f,a1=0.f;
    const float4* w1 = (const float4*)(lstm_wih + (size_t)u*256);
    const float4* w2 = (const float4*)(lstm_whh + (size_t)u*256);
    const float4* fv = (const float4*)feat;
    const float4* hv = (const float4*)hxs;
    for (int k=0;k<64;++k){
      float4 wa = w1[k], fa = fv[k];
      a0 += wa.x*fa.x + wa.y*fa.y + wa.z*fa.z + wa.w*fa.w;
      float4 wb = w2[k], ha = hv[k];
      a1 += wb.x*ha.x + wb.y*ha.y + wb.z*ha.z + wb.w*ha.w;
    }
    g[u] = lstm_bih[u] + lstm_bhh[u] + a0 + a1;
  }
  __syncthreads();

  if (u < 256){
    float ii=g[u], ff=g[256+u], gg=g[512+u], oo=g[768+u];
    float c2 = sigf(ff)*cxs[u] + sigf(ii)*tanhf(gg);
    float h2 = sigf(oo)*tanhf(c2);
    z[u] = h2;
    out[5+u]   = h2;
    out[261+u] = c2;
  }
  if (u >= 256 && u < 288){
    int e2 = u-256;
    z[u] = time_emb[(size_t)tx[0]*32 + e2];
  }
  __syncthreads();

  if (u == 0){
    float a = crit_b[0];
    for (int k=0;k<288;++k) a += z[k]*crit_w[k];
    out[0] = a;
  } else if (u < 5){
    int r = u-1;
    float a = act_b[r];
    for (int k=0;k<288;++k) a += z[k]*act_w[(size_t)r*288+k];
    out[1+r] = a;
  }
}

// ---------------------------------------------------------------------------
extern "C" void kernel_launch(void* const* d_in, const int* in_sizes, int n_in,
                              void* d_out, int out_size, void* d_ws, size_t ws_size,
                              hipStream_t stream)
{
  const float* x        = (const float*)d_in[0];
  const float* hx       = (const float*)d_in[1];
  const float* cx       = (const float*)d_in[2];
  const int*  prev      = (const int*)d_in[3];
  const int*  curr      = (const int*)d_in[4];
  const int*  nxt       = (const int*)d_in[5];
  const int*  tx        = (const int*)d_in[6];
  const float* emb      = (const float*)d_in[7];
  const float* gru_wih  = (const float*)d_in[8];
  const float* gru_whh  = (const float*)d_in[9];
  const float* gru_bih  = (const float*)d_in[10];
  const float* gru_bhh  = (const float*)d_in[11];
  const float* conv1_w  = (const float*)d_in[12];
  const float* conv1_b  = (const float*)d_in[13];
  const float* conv2_w  = (const float*)d_in[14];
  const float* conv2_b  = (const float*)d_in[15];
  const float* conv3_w  = (const float*)d_in[16];
  const float* conv3_b  = (const float*)d_in[17];
  const float* img_w    = (const float*)d_in[18];
  const float* img_b    = (const float*)d_in[19];
  const float* akp_w    = (const float*)d_in[20];
  const float* akp_b    = (const float*)d_in[21];
  const float* akn_w    = (const float*)d_in[22];
  const float* akn_b    = (const float*)d_in[23];
  const float* bil_p_w  = (const float*)d_in[24];
  const float* bil_p_b  = (const float*)d_in[25];
  const float* bil_n_w  = (const float*)d_in[26];
  const float* bil_n_b  = (const float*)d_in[27];
  const float* pred_w   = (const float*)d_in[28];
  const float* pred_b   = (const float*)d_in[29];
  const float* nred_w   = (const float*)d_in[30];
  const float* nred_b   = (const float*)d_in[31];
  const float* gate_w   = (const float*)d_in[32];
  const float* gate_b   = (const float*)d_in[33];
  const float* lin_w    = (const float*)d_in[34];
  const float* lin_b    = (const float*)d_in[35];
  const float* lstm_wih = (const float*)d_in[36];
  const float* lstm_whh = (const float*)d_in[37];
  const float* lstm_bih = (const float*)d_in[38];
  const float* lstm_bhh = (const float*)d_in[39];
  const float* time_emb = (const float*)d_in[40];
  const float* crit_w   = (const float*)d_in[41];
  const float* crit_b   = (const float*)d_in[42];
  const float* act_w    = (const float*)d_in[43];
  const float* act_b    = (const float*)d_in[44];

  float* ws = (float*)d_ws;
  float* gi    = ws + GI_OFF;
  float* hf    = ws + HF_OFF;
  float* hb    = ws + HB_OFF;
  float* x1    = ws + X1_OFF;
  float* x2    = ws + X2_OFF;
  float* ximg  = ws + XIMG_OFF;
  float* akin  = ws + AKIN_OFF;
  float* psum  = ws + PSUM_OFF;
  float* nsum  = ws + NSUM_OFF;

  float* out = (float*)d_out;

  gi_kernel      <<<160, 256, 0, stream>>>(emb, gru_wih, gru_bih, prev, curr, nxt, gi);
  gru_scan_kernel<<<6,  1024, 0, stream>>>(gru_whh, gru_bhh, gi, hf, hb);
  conv1_kernel   <<<450, 256, 0, stream>>>(x, conv1_w, conv1_b, x1);
  conv2_kernel   <<<49,  256, 0, stream>>>(x1, conv2_w, conv2_b, x2);
  conv3_kernel   <<<9,   256, 0, stream>>>(x2, conv3_w, conv3_b, ximg);
  imgemb_kernel  <<<1,   256, 0, stream>>>(ximg, img_w, img_b, hf, hb, akin);
  attend_kernel  <<<2,   512, 0, stream>>>(akin, akp_w, akp_b, akn_w, akn_b,
                                           bil_p_w, bil_p_b, bil_n_w, bil_n_b,
                                           hf, hb, psum, nsum);
  head_kernel    <<<1,  1024, 0, stream>>>(psum, nsum, akin, ximg,
                                           pred_w, pred_b, nred_w, nred_b,
                                           gate_w, gate_b, lin_w, lin_b,
                                           lstm_wih, lstm_whh, lstm_bih, lstm_bhh,
                                           hx, cx, tx, time_emb,
                                           crit_w, crit_b, act_w, act_b, out);
}

// Round 4
// 1133.942 us; speedup vs baseline: 9.6602x; 9.6602x over previous
//
#include <hip/hip_runtime.h>
#include <hip/hip_bf16.h>

typedef unsigned int u32;
typedef _Float16 f16x8 __attribute__((ext_vector_type(8)));
typedef float f32x4 __attribute__((ext_vector_type(4)));

__device__ __forceinline__ float sigf(float x){ return 1.0f/(1.0f + __expf(-x)); }

// ---------------------------------------------------------------------------
// ws layout (float offsets)
// ---------------------------------------------------------------------------
#define GI_OFF   0
#define GI_SZ    (2560*768)
#define HF_OFF   (GI_OFF + GI_SZ)
#define HF_SZ    (1280*256)
#define HB_OFF   (HF_OFF + HF_SZ)
#define X1_OFF   (HB_OFF + HF_SZ)
#define X1_SZ    (128*30*30)
#define X2_OFF   (X1_OFF + X1_SZ)
#define X2_SZ    (64*14*14)
#define XIMG_OFF (X2_OFF + X2_SZ)
#define XIMG_SZ  (64*6*6)
#define AKIN_OFF (XIMG_OFF + XIMG_SZ)
#define PSUM_OFF (AKIN_OFF + 768)
#define NSUM_OFF (PSUM_OFF + 512)

// ---------------- gi precompute: gi[row][768] = emb[tok] @ wih[j].T + bih[j] ----
__global__ __launch_bounds__(256) void gi_kernel(
    const float* __restrict__ emb, const float* __restrict__ wih_all,
    const float* __restrict__ bih_all,
    const int* __restrict__ prev, const int* __restrict__ curr, const int* __restrict__ nxt,
    float* __restrict__ gi_all)
{
  const int offs[7] = {0,512,768,1280,1792,2048,2560};
  int row0 = blockIdx.x * 16;
  int j = 0;
  while (row0 >= offs[j+1]) ++j;
  int t0 = row0 - offs[j];
  int sel = j % 3;
  const int* inst = (sel==0)? prev : (sel==1)? curr : nxt;

  __shared__ __align__(16) float e[16][32];
  int u = threadIdx.x;
  for (int idx=u; idx<512; idx+=256){
    int r = idx >> 5, k = idx & 31;
    e[r][k] = emb[(size_t)inst[t0+r]*32 + k];
  }
  __syncthreads();

  const float* wih = wih_all + (size_t)j*768*32;
  const float* bih = bih_all + (size_t)j*768;
  for (int g3=0; g3<3; ++g3){
    int o = g3*256 + u;
    float bb = bih[o];
    float acc[16];
#pragma unroll
    for (int r=0;r<16;++r) acc[r]=bb;
    const float* wr = wih + (size_t)o*32;
#pragma unroll
    for (int k=0;k<32;++k){
      float w = wr[k];
#pragma unroll
      for (int r=0;r<16;++r) acc[r] += w * e[r][k];
    }
    for (int r=0;r<16;++r) gi_all[(size_t)(row0+r)*768 + o] = acc[r];
  }
}

// ---------------- GRU sequential scan: 6 blocks, one per GRU -------------------
// 512 threads = 8 waves. Wave w owns row-tiles w*6..w*6+5 (16 rows each).
// A (whh, f32->f16 once) lives in 192 VGPRs/lane as MFMA fragments.
// Recurrent matvec per step: 48 x mfma_f32_16x16x32_f16 per wave, B = broadcast h.
__global__ __launch_bounds__(512,2) void gru_scan_kernel(
    const float* __restrict__ whh_all, const float* __restrict__ bhh_all,
    const float* __restrict__ gi_all, float* __restrict__ hf, float* __restrict__ hb)
{
  const int lens[6] = {512,256,512,512,256,512};
  const int offs[6] = {0,512,768,1280,1792,2048};
  int j = blockIdx.x;
  int u = threadIdx.x;
  int len = lens[j];
  const float* gi = gi_all + (size_t)offs[j]*768;
  float* outp = ((j<3)? hf : hb) + (size_t)offs[j%3]*256;

  int w    = u >> 6;   // wave 0..7
  int l    = u & 63;   // lane
  int arow = l & 15;   // A row within tile / D col
  int kgrp = l >> 4;   // k-group 0..3

  // ---- load A fragments: af[i][kt] = W[16*(w*6+i)+arow][32*kt+8*kgrp .. +8) as f16
  f16x8 af[6][8];
  {
    const float* Wj = whh_all + (size_t)j*768*256;
#pragma unroll
    for (int i=0;i<6;++i){
      const float* wrow = Wj + (size_t)(16*(w*6+i) + arow)*256;
#pragma unroll
      for (int kt=0;kt<8;++kt){
        const float4* p = (const float4*)(wrow + 32*kt + 8*kgrp);
        float4 c0 = p[0], c1 = p[1];
        f16x8 v;
        v[0]=(_Float16)c0.x; v[1]=(_Float16)c0.y; v[2]=(_Float16)c0.z; v[3]=(_Float16)c0.w;
        v[4]=(_Float16)c1.x; v[5]=(_Float16)c1.y; v[6]=(_Float16)c1.z; v[7]=(_Float16)c1.w;
        af[i][kt] = v;
      }
    }
  }

  float bh0=0.f, bh1=0.f, bh2=0.f, hprev=0.f;
  if (u < 256){
    bh0 = bhh_all[j*768 + u];
    bh1 = bhh_all[j*768 + 256 + u];
    bh2 = bhh_all[j*768 + 512 + u];
  }

  __shared__ __align__(16) _Float16 h16[256];
  __shared__ __align__(16) float gacc[768];
  if (u < 256) h16[u] = (_Float16)0.0f;
  __syncthreads();

  for (int t=0; t<len; ++t){
    // issue gi loads early; consumed after barrier (hides L2/HBM latency)
    float gr=0.f, gz=0.f, gn=0.f;
    if (u < 256){
      const float* git = gi + (size_t)t*768;
      gr = git[u]; gz = git[256+u]; gn = git[512+u];
    }

    // W @ h via MFMA: B fragment = h slice broadcast to all 16 cols
    f32x4 acc[6];
#pragma unroll
    for (int i=0;i<6;++i){ f32x4 zz = {0.f,0.f,0.f,0.f}; acc[i] = zz; }
#pragma unroll
    for (int kt=0; kt<8; ++kt){
      f16x8 bfr = *(const f16x8*)(h16 + 32*kt + 8*kgrp);
#pragma unroll
      for (int i=0;i<6;++i)
        acc[i] = __builtin_amdgcn_mfma_f32_16x16x32_f16(af[i][kt], bfr, acc[i], 0, 0, 0);
    }
    // col 0 of D = W@h rows; lane arow==0 holds rows 16*tt + 4*kgrp + {0..3}
    if (arow == 0){
#pragma unroll
      for (int i=0;i<6;++i){
        float4 v; v.x=acc[i][0]; v.y=acc[i][1]; v.z=acc[i][2]; v.w=acc[i][3];
        *(float4*)&gacc[16*(w*6+i) + 4*kgrp] = v;
      }
    }
    __syncthreads();

    if (u < 256){
      float r  = sigf(gr + bh0 + gacc[u]);
      float z  = sigf(gz + bh1 + gacc[256+u]);
      float n  = tanhf(gn + bh2 + r*gacc[512+u]);
      float h2 = (1.0f - z)*n + z*hprev;
      outp[(size_t)t*256 + u] = h2;
      h16[u] = (_Float16)h2;
      hprev = h2;
    }
    __syncthreads();
  }
}

// ---------------- convs (direct, one thread per output) ------------------------
__global__ __launch_bounds__(256) void conv1_kernel(
    const float* __restrict__ x, const float* __restrict__ w, const float* __restrict__ b,
    float* __restrict__ y)
{
  int idx = blockIdx.x*256 + threadIdx.x;
  if (idx >= 128*30*30) return;
  int c = idx/900, rem = idx%900, i = rem/30, jx = rem%30;
  float acc = b[c];
  const float* wc = w + (size_t)c*3*8*8;
  for (int ic=0; ic<3; ++ic)
    for (int ky=0; ky<8; ++ky){
      const float* xrow = x + ((size_t)ic*124 + (i*4+ky))*124 + jx*4;
      const float* wrow = wc + (ic*8+ky)*8;
#pragma unroll
      for (int kx=0; kx<8; ++kx) acc += xrow[kx] * wrow[kx];
    }
  y[idx] = fmaxf(acc, 0.0f);
}

__global__ __launch_bounds__(256) void conv2_kernel(
    const float* __restrict__ x1, const float* __restrict__ w, const float* __restrict__ b,
    float* __restrict__ y)
{
  int idx = blockIdx.x*256 + threadIdx.x;
  if (idx >= 64*14*14) return;
  int c = idx/196, rem = idx%196, i = rem/14, jx = rem%14;
  float acc = b[c];
  for (int ic=0; ic<128; ++ic){
    const float* xc = x1 + (size_t)ic*900;
    const float* wc = w + ((size_t)c*128 + ic)*16;
#pragma unroll
    for (int ky=0; ky<4; ++ky)
#pragma unroll
      for (int kx=0; kx<4; ++kx)
        acc += xc[(i*2+ky)*30 + (jx*2+kx)] * wc[ky*4+kx];
  }
  y[idx] = fmaxf(acc, 0.0f);
}

__global__ __launch_bounds__(256) void conv3_kernel(
    const float* __restrict__ x2, const float* __restrict__ w, const float* __restrict__ b,
    float* __restrict__ y)
{
  int idx = blockIdx.x*256 + threadIdx.x;
  if (idx >= 64*6*6) return;
  int c = idx/36, rem = idx%36, i = rem/6, jx = rem%6;
  float acc = b[c];
  for (int ic=0; ic<64; ++ic){
    const float* xc = x2 + (size_t)ic*196;
    const float* wc = w + ((size_t)c*64 + ic)*16;
#pragma unroll
    for (int ky=0; ky<4; ++ky)
#pragma unroll
      for (int kx=0; kx<4; ++kx)
        acc += xc[(i*2+ky)*14 + (jx*2+kx)] * wc[ky*4+kx];
  }
  y[idx] = fmaxf(acc, 0.0f);
}

// ---------------- image embedding + ak_in assembly -----------------------------
__global__ __launch_bounds__(256) void imgemb_kernel(
    const float* __restrict__ x_img, const float* __restrict__ img_w, const float* __restrict__ img_b,
    const float* __restrict__ hf, const float* __restrict__ hb, float* __restrict__ ak_in)
{
  __shared__ __align__(16) float xs[2304];
  int u = threadIdx.x;
  for (int i=u; i<2304; i+=256) xs[i] = x_img[i];
  __syncthreads();
  float a0=0.f,a1=0.f,a2=0.f,a3=0.f;
  const float4* wr = (const float4*)(img_w + (size_t)u*2304);
  const float4* xv = (const float4*)xs;
  for (int k=0; k<576; ++k){
    float4 w = wr[k], xx = xv[k];
    a0 += w.x*xx.x; a1 += w.y*xx.y; a2 += w.z*xx.z; a3 += w.w*xx.w;
  }
  ak_in[512+u] = img_b[u] + ((a0+a1)+(a2+a3)); // image_emb
  ak_in[u]     = hf[(size_t)767*256+u];        // curr_rep fwd half
  ak_in[256+u] = hb[(size_t)767*256+u];        // curr_rep bwd half (rb[P])
}

// ---------------- attention (block 0 = prev, block 1 = next) -------------------
__global__ __launch_bounds__(512) void attend_kernel(
    const float* __restrict__ ak_in_g,
    const float* __restrict__ akp_w, const float* __restrict__ akp_b,
    const float* __restrict__ akn_w, const float* __restrict__ akn_b,
    const float* __restrict__ bil_p_w, const float* __restrict__ bil_p_b,
    const float* __restrict__ bil_n_w, const float* __restrict__ bil_n_b,
    const float* __restrict__ hf, const float* __restrict__ hb,
    float* __restrict__ prev_sum, float* __restrict__ next_sum)
{
  int blk = blockIdx.x;
  const float* akw = blk? akn_w : akp_w;
  const float* akb = blk? akn_b : akp_b;
  const float* bw  = blk? bil_n_w : bil_p_w;
  float bb         = blk? bil_n_b[0] : bil_p_b[0];
  float* outp      = blk? next_sum : prev_sum;

  int u = threadIdx.x;
  __shared__ __align__(16) float ak[768];
  __shared__ __align__(16) float kk[256];
  __shared__ __align__(16) float q[512];
  __shared__ float s[512], red[512];

  for (int i=u; i<768; i+=512) ak[i] = ak_in_g[i];
  __syncthreads();

  if (u < 256){
    float a0=0.f,a1=0.f,a2=0.f,a3=0.f;
    const float4* wr = (const float4*)(akw + (size_t)u*768);
    const float4* av = (const float4*)ak;
    for (int m=0; m<192; ++m){
      float4 w = wr[m], aa = av[m];
      a0 += w.x*aa.x; a1 += w.y*aa.y; a2 += w.z*aa.z; a3 += w.w*aa.w;
    }
    kk[u] = akb[u] + ((a0+a1)+(a2+a3));
  }
  __syncthreads();

  { // q = k @ bw[0]   (coalesced: lane u reads column u)
    float acc = 0.0f;
    for (int m=0; m<256; ++m) acc += kk[m]*bw[(size_t)m*512 + u];
    q[u] = acc;
  }
  __syncthreads();

  { // scores: s[i] = q . rep[i] + bb
    int i = u;
    const float4* repf = (const float4*)(hf + (size_t)(blk? (768+i) : i)*256);
    const float4* repb = (const float4*)(hb + (size_t)(blk? (511-i) : (1279-i))*256);
    const float4* qf = (const float4*)q;
    float a0=0.f,a1=0.f;
    for (int v=0; v<64; ++v){
      float4 qq = qf[v],  rr = repf[v];
      a0 += qq.x*rr.x + qq.y*rr.y + qq.z*rr.z + qq.w*rr.w;
      float4 q2 = qf[64+v], r2 = repb[v];
      a1 += q2.x*r2.x + q2.y*r2.y + q2.z*r2.z + q2.w*r2.w;
    }
    s[u] = bb + a0 + a1;
  }
  __syncthreads();

  // softmax over 512
  red[u] = s[u]; __syncthreads();
  for (int st=256; st>0; st>>=1){ if (u<st) red[u]=fmaxf(red[u],red[u+st]); __syncthreads(); }
  float mx = red[0]; __syncthreads();
  float ex = __expf(s[u]-mx);
  red[u] = ex; __syncthreads();
  for (int st=256; st>0; st>>=1){ if (u<st) red[u]+=red[u+st]; __syncthreads(); }
  float inv = 1.0f/red[0]; __syncthreads();
  s[u] = ex*inv;
  __syncthreads();

  // weighted sum over rows (coalesced: lane reads column u)
  float o = 0.0f;
  if (u < 256){
    for (int r=0; r<512; ++r){
      const float* rf = hf + (size_t)(blk? (768+r) : r)*256;
      o += s[r]*rf[u];
    }
    outp[u] = o;
  } else {
    int v = u-256;
    for (int r=0; r<512; ++r){
      const float* rb = hb + (size_t)(blk? (511-r) : (1279-r))*256;
      o += s[r]*rb[v];
    }
    outp[u] = o;
  }
}

// ---------------- head: pred/nred, gate, lin, LSTM, outputs --------------------
__global__ __launch_bounds__(1024) void head_kernel(
    const float* __restrict__ prev_sum_g, const float* __restrict__ next_sum_g,
    const float* __restrict__ ak_in_g, const float* __restrict__ x_img,
    const float* __restrict__ pred_w, const float* __restrict__ pred_b,
    const float* __restrict__ nred_w, const float* __restrict__ nred_b,
    const float* __restrict__ gate_w, const float* __restrict__ gate_b,
    const float* __restrict__ lin_w,  const float* __restrict__ lin_b,
    const float* __restrict__ lstm_wih, const float* __restrict__ lstm_whh,
    const float* __restrict__ lstm_bih, const float* __restrict__ lstm_bhh,
    const float* __restrict__ hx, const float* __restrict__ cx,
    const int* __restrict__ tx, const float* __restrict__ time_emb,
    const float* __restrict__ crit_w, const float* __restrict__ crit_b,
    const float* __restrict__ act_w,  const float* __restrict__ act_b,
    float* __restrict__ out)
{
  int u = threadIdx.x;
  __shared__ __align__(16) float ps[512];
  __shared__ __align__(16) float ns[512];
  __shared__ __align__(16) float cr[512];
  __shared__ float pg[64], ng[64], gate[64];
  __shared__ __align__(16) float xg[2304];
  __shared__ __align__(16) float feat[256];
  __shared__ __align__(16) float hxs[256];
  __shared__ float g[1024], cxs[256], z[288];

  if (u < 512){ ps[u]=prev_sum_g[u]; ns[u]=next_sum_g[u]; cr[u]=ak_in_g[u]; }
  if (u >= 512 && u < 768){ int t=u-512; hxs[t]=hx[t]; cxs[t]=cx[t]; }
  for (int i=u; i<2304; i+=1024) xg[i] = x_img[i];
  __syncthreads();

  if (u < 64){
    float a = pred_b[u];
    const float* wr = pred_w + (size_t)u*512;
    for (int k=0;k<512;++k) a += ps[k]*wr[k];
    pg[u] = a;
  } else if (u < 128){
    int t = u-64;
    float a = nred_b[t];
    const float* wr = nred_w + (size_t)t*512;
    for (int k=0;k<512;++k) a += ns[k]*wr[k];
    ng[t] = a;
  }
  __syncthreads();

  if (u < 64){
    float a = gate_b[u];
    const float* wr = gate_w + (size_t)u*640;
    for (int k=0;k<512;++k) a += cr[k]*wr[k];
    for (int k=0;k<64;++k)  a += pg[k]*wr[512+k];
    for (int k=0;k<64;++k)  a += ng[k]*wr[576+k];
    gate[u] = sigf(a);
  }
  __syncthreads();

  for (int i=u; i<2304; i+=1024) xg[i] *= gate[i/36];
  __syncthreads();

  if (u < 256){
    float a0=0.f,a1=0.f,a2=0.f,a3=0.f;
    const float4* wr = (const float4*)(lin_w + (size_t)u*2304);
    const float4* xv = (const float4*)xg;
    for (int k=0;k<576;++k){
      float4 w = wr[k], xx = xv[k];
      a0 += w.x*xx.x; a1 += w.y*xx.y; a2 += w.z*xx.z; a3 += w.w*xx.w;
    }
    feat[u] = fmaxf(lin_b[u] + ((a0+a1)+(a2+a3)), 0.0f);
  }
  __syncthreads();

  {
    float a0=0.f,a1=0.f;
    const float4* w1 = (const float4*)(lstm_wih + (size_t)u*256);
    const float4* w2 = (const float4*)(lstm_whh + (size_t)u*256);
    const float4* fv = (const float4*)feat;
    const float4* hv = (const float4*)hxs;
    for (int k=0;k<64;++k){
      float4 wa = w1[k], fa = fv[k];
      a0 += wa.x*fa.x + wa.y*fa.y + wa.z*fa.z + wa.w*fa.w;
      float4 wb = w2[k], ha = hv[k];
      a1 += wb.x*ha.x + wb.y*ha.y + wb.z*ha.z + wb.w*ha.w;
    }
    g[u] = lstm_bih[u] + lstm_bhh[u] + a0 + a1;
  }
  __syncthreads();

  if (u < 256){
    float ii=g[u], ff=g[256+u], gg=g[512+u], oo=g[768+u];
    float c2 = sigf(ff)*cxs[u] + sigf(ii)*tanhf(gg);
    float h2 = sigf(oo)*tanhf(c2);
    z[u] = h2;
    out[5+u]   = h2;
    out[261+u] = c2;
  }
  if (u >= 256 && u < 288){
    int e2 = u-256;
    z[u] = time_emb[(size_t)tx[0]*32 + e2];
  }
  __syncthreads();

  if (u == 0){
    float a = crit_b[0];
    for (int k=0;k<288;++k) a += z[k]*crit_w[k];
    out[0] = a;
  } else if (u < 5){
    int r = u-1;
    float a = act_b[r];
    for (int k=0;k<288;++k) a += z[k]*act_w[(size_t)r*288+k];
    out[1+r] = a;
  }
}

// ---------------------------------------------------------------------------
extern "C" void kernel_launch(void* const* d_in, const int* in_sizes, int n_in,
                              void* d_out, int out_size, void* d_ws, size_t ws_size,
                              hipStream_t stream)
{
  const float* x        = (const float*)d_in[0];
  const float* hx       = (const float*)d_in[1];
  const float* cx       = (const float*)d_in[2];
  const int*  prev      = (const int*)d_in[3];
  const int*  curr      = (const int*)d_in[4];
  const int*  nxt       = (const int*)d_in[5];
  const int*  tx        = (const int*)d_in[6];
  const float* emb      = (const float*)d_in[7];
  const float* gru_wih  = (const float*)d_in[8];
  const float* gru_whh  = (const float*)d_in[9];
  const float* gru_bih  = (const float*)d_in[10];
  const float* gru_bhh  = (const float*)d_in[11];
  const float* conv1_w  = (const float*)d_in[12];
  const float* conv1_b  = (const float*)d_in[13];
  const float* conv2_w  = (const float*)d_in[14];
  const float* conv2_b  = (const float*)d_in[15];
  const float* conv3_w  = (const float*)d_in[16];
  const float* conv3_b  = (const float*)d_in[17];
  const float* img_w    = (const float*)d_in[18];
  const float* img_b    = (const float*)d_in[19];
  const float* akp_w    = (const float*)d_in[20];
  const float* akp_b    = (const float*)d_in[21];
  const float* akn_w    = (const float*)d_in[22];
  const float* akn_b    = (const float*)d_in[23];
  const float* bil_p_w  = (const float*)d_in[24];
  const float* bil_p_b  = (const float*)d_in[25];
  const float* bil_n_w  = (const float*)d_in[26];
  const float* bil_n_b  = (const float*)d_in[27];
  const float* pred_w   = (const float*)d_in[28];
  const float* pred_b   = (const float*)d_in[29];
  const float* nred_w   = (const float*)d_in[30];
  const float* nred_b   = (const float*)d_in[31];
  const float* gate_w   = (const float*)d_in[32];
  const float* gate_b   = (const float*)d_in[33];
  const float* lin_w    = (const float*)d_in[34];
  const float* lin_b    = (const float*)d_in[35];
  const float* lstm_wih = (const float*)d_in[36];
  const float* lstm_whh = (const float*)d_in[37];
  const float* lstm_bih = (const float*)d_in[38];
  const float* lstm_bhh = (const float*)d_in[39];
  const float* time_emb = (const float*)d_in[40];
  const float* crit_w   = (const float*)d_in[41];
  const float* crit_b   = (const float*)d_in[42];
  const float* act_w    = (const float*)d_in[43];
  const float* act_b    = (const float*)d_in[44];

  float* ws = (float*)d_ws;
  float* gi    = ws + GI_OFF;
  float* hf    = ws + HF_OFF;
  float* hb    = ws + HB_OFF;
  float* x1    = ws + X1_OFF;
  float* x2    = ws + X2_OFF;
  float* ximg  = ws + XIMG_OFF;
  float* akin  = ws + AKIN_OFF;
  float* psum  = ws + PSUM_OFF;
  float* nsum  = ws + NSUM_OFF;

  float* out = (float*)d_out;

  gi_kernel      <<<160, 256, 0, stream>>>(emb, gru_wih, gru_bih, prev, curr, nxt, gi);
  gru_scan_kernel<<<6,   512, 0, stream>>>(gru_whh, gru_bhh, gi, hf, hb);
  conv1_kernel   <<<450, 256, 0, stream>>>(x, conv1_w, conv1_b, x1);
  conv2_kernel   <<<49,  256, 0, stream>>>(x1, conv2_w, conv2_b, x2);
  conv3_kernel   <<<9,   256, 0, stream>>>(x2, conv3_w, conv3_b, ximg);
  imgemb_kernel  <<<1,   256, 0, stream>>>(ximg, img_w, img_b, hf, hb, akin);
  attend_kernel  <<<2,   512, 0, stream>>>(akin, akp_w, akp_b, akn_w, akn_b,
                                           bil_p_w, bil_p_b, bil_n_w, bil_n_b,
                                           hf, hb, psum, nsum);
  head_kernel    <<<1,  1024, 0, stream>>>(psum, nsum, akin, ximg,
                                           pred_w, pred_b, nred_w, nred_b,
                                           gate_w, gate_b, lin_w, lin_b,
                                           lstm_wih, lstm_whh, lstm_bih, lstm_bhh,
                                           hx, cx, tx, time_emb,
                                           crit_w, crit_b, act_w, act_b, out);
}

// Round 5
// 1097.833 us; speedup vs baseline: 9.9780x; 1.0329x over previous
//
#include <hip/hip_runtime.h>
#include <hip/hip_bf16.h>

typedef unsigned int u32;
typedef _Float16 f16x8 __attribute__((ext_vector_type(8)));
typedef float f32x4 __attribute__((ext_vector_type(4)));

__device__ __forceinline__ float sigf(float x){ return 1.0f/(1.0f + __expf(-x)); }
__device__ __forceinline__ float tanhfast(float x){
  float xc = fminf(fmaxf(x, -15.0f), 15.0f);
  float e = __expf(2.0f*xc);
  return (e - 1.0f)/(e + 1.0f);
}

// ---------------------------------------------------------------------------
// ws layout (float offsets)
// ---------------------------------------------------------------------------
#define GI_OFF   0
#define GI_SZ    (2560*768)
#define HF_OFF   (GI_OFF + GI_SZ)
#define HF_SZ    (1280*256)
#define HB_OFF   (HF_OFF + HF_SZ)
#define X1_OFF   (HB_OFF + HF_SZ)
#define X1_SZ    (128*30*30)
#define X2_OFF   (X1_OFF + X1_SZ)
#define X2_SZ    (64*14*14)
#define XIMG_OFF (X2_OFF + X2_SZ)
#define XIMG_SZ  (64*6*6)
#define AKIN_OFF (XIMG_OFF + XIMG_SZ)
#define PSUM_OFF (AKIN_OFF + 768)
#define NSUM_OFF (PSUM_OFF + 512)
#define GATE_OFF (NSUM_OFF + 512)
#define FEAT_OFF (GATE_OFF + 64)
#define G_OFF    (FEAT_OFF + 256)

// ---------------- gi precompute: gi[row][768] = emb[tok] @ wih[j].T + bih[j] ----
__global__ __launch_bounds__(256) void gi_kernel(
    const float* __restrict__ emb, const float* __restrict__ wih_all,
    const float* __restrict__ bih_all,
    const int* __restrict__ prev, const int* __restrict__ curr, const int* __restrict__ nxt,
    float* __restrict__ gi_all)
{
  const int offs[7] = {0,512,768,1280,1792,2048,2560};
  int row0 = blockIdx.x * 16;
  int j = 0;
  while (row0 >= offs[j+1]) ++j;
  int t0 = row0 - offs[j];
  int sel = j % 3;
  const int* inst = (sel==0)? prev : (sel==1)? curr : nxt;

  __shared__ __align__(16) float e[16][32];
  int u = threadIdx.x;
  for (int idx=u; idx<512; idx+=256){
    int r = idx >> 5, k = idx & 31;
    e[r][k] = emb[(size_t)inst[t0+r]*32 + k];
  }
  __syncthreads();

  const float* wih = wih_all + (size_t)j*768*32;
  const float* bih = bih_all + (size_t)j*768;
  for (int g3=0; g3<3; ++g3){
    int o = g3*256 + u;
    float bb = bih[o];
    float acc[16];
#pragma unroll
    for (int r=0;r<16;++r) acc[r]=bb;
    const float* wr = wih + (size_t)o*32;
#pragma unroll
    for (int k=0;k<32;++k){
      float w = wr[k];
#pragma unroll
      for (int r=0;r<16;++r) acc[r] += w * e[r][k];
    }
    for (int r=0;r<16;++r) gi_all[(size_t)(row0+r)*768 + o] = acc[r];
  }
}

// ---------------- GRU sequential scan: 6 blocks, one per GRU -------------------
// 256 threads = 4 waves, 1 wave/SIMD, reg budget 512 (launch_bounds(256,1)).
// Wave w owns 12 row-tiles (16 rows each): af[12][8] = 384 regs, resident.
// Per step: 96 MFMA/wave (3 groups x 4 tiles x 8 k-steps), B = broadcast h16.
__global__ __launch_bounds__(256,1) void gru_scan_kernel(
    const float* __restrict__ whh_all, const float* __restrict__ bhh_all,
    const float* __restrict__ gi_all, float* __restrict__ hf, float* __restrict__ hb)
{
  const int lens[6] = {512,256,512,512,256,512};
  const int offs[6] = {0,512,768,1280,1792,2048};
  int j = blockIdx.x;
  int u = threadIdx.x;
  int len = lens[j];
  const float* gi = gi_all + (size_t)offs[j]*768;
  float* outp = ((j<3)? hf : hb) + (size_t)offs[j%3]*256;

  int w    = u >> 6;   // wave 0..3
  int l    = u & 63;
  int arow = l & 15;   // A row within tile / D col
  int kgrp = l >> 4;   // k-group 0..3

  // A fragments: af[i][kt] = W[16*(w*12+i)+arow][32*kt+8*kgrp .. +8) as f16
  f16x8 af[12][8];
  {
    const float* Wj = whh_all + (size_t)j*768*256;
#pragma unroll
    for (int i=0;i<12;++i){
      const float* wrow = Wj + (size_t)(16*(w*12+i) + arow)*256;
#pragma unroll
      for (int kt=0;kt<8;++kt){
        const float4* p = (const float4*)(wrow + 32*kt + 8*kgrp);
        float4 c0 = p[0], c1 = p[1];
        f16x8 v;
        v[0]=(_Float16)c0.x; v[1]=(_Float16)c0.y; v[2]=(_Float16)c0.z; v[3]=(_Float16)c0.w;
        v[4]=(_Float16)c1.x; v[5]=(_Float16)c1.y; v[6]=(_Float16)c1.z; v[7]=(_Float16)c1.w;
        af[i][kt] = v;
      }
    }
  }

  float bh0 = bhh_all[j*768 + u];
  float bh1 = bhh_all[j*768 + 256 + u];
  float bh2 = bhh_all[j*768 + 512 + u];
  float hprev = 0.0f;

  __shared__ __align__(16) _Float16 h16[256];
  __shared__ __align__(16) float gacc[768];
  h16[u] = (_Float16)0.0f;
  __syncthreads();

  for (int t=0; t<len; ++t){
    // delayed store of previous h (drains during MFMA phase, not at a barrier)
    if (t > 0) outp[(size_t)(t-1)*256 + u] = hprev;
    // gi prefetch (consumed after barrier 1)
    const float* git = gi + (size_t)t*768;
    float gr = git[u], gz = git[256+u], gn = git[512+u];

    // W @ h via MFMA, 3 groups of 4 tiles (keeps acc footprint small)
#pragma unroll
    for (int g=0; g<3; ++g){
      f32x4 acc[4];
#pragma unroll
      for (int i=0;i<4;++i){ f32x4 zz = {0.f,0.f,0.f,0.f}; acc[i] = zz; }
#pragma unroll
      for (int kt=0; kt<8; ++kt){
        f16x8 bfr = *(const f16x8*)(h16 + 32*kt + 8*kgrp);
#pragma unroll
        for (int i=0;i<4;++i)
          acc[i] = __builtin_amdgcn_mfma_f32_16x16x32_f16(af[g*4+i][kt], bfr, acc[i], 0, 0, 0);
      }
      if (arow == 0){
#pragma unroll
        for (int i=0;i<4;++i){
          float4 v; v.x=acc[i][0]; v.y=acc[i][1]; v.z=acc[i][2]; v.w=acc[i][3];
          *(float4*)&gacc[16*(w*12 + g*4 + i) + 4*kgrp] = v;
        }
      }
    }
    __syncthreads();

    float r  = sigf(gr + bh0 + gacc[u]);
    float z  = sigf(gz + bh1 + gacc[256+u]);
    float n  = tanhfast(gn + bh2 + r*gacc[512+u]);
    float h2 = (1.0f - z)*n + z*hprev;
    h16[u] = (_Float16)h2;
    hprev = h2;
    __syncthreads();
  }
  outp[(size_t)(len-1)*256 + u] = hprev;
}

// ---------------- convs (direct, one thread per output) ------------------------
__global__ __launch_bounds__(256) void conv1_kernel(
    const float* __restrict__ x, const float* __restrict__ w, const float* __restrict__ b,
    float* __restrict__ y)
{
  int idx = blockIdx.x*256 + threadIdx.x;
  if (idx >= 128*30*30) return;
  int c = idx/900, rem = idx%900, i = rem/30, jx = rem%30;
  float acc = b[c];
  const float* wc = w + (size_t)c*3*8*8;
  for (int ic=0; ic<3; ++ic)
    for (int ky=0; ky<8; ++ky){
      const float* xrow = x + ((size_t)ic*124 + (i*4+ky))*124 + jx*4;
      const float* wrow = wc + (ic*8+ky)*8;
#pragma unroll
      for (int kx=0; kx<8; ++kx) acc += xrow[kx] * wrow[kx];
    }
  y[idx] = fmaxf(acc, 0.0f);
}

__global__ __launch_bounds__(256) void conv2_kernel(
    const float* __restrict__ x1, const float* __restrict__ w, const float* __restrict__ b,
    float* __restrict__ y)
{
  int idx = blockIdx.x*256 + threadIdx.x;
  if (idx >= 64*14*14) return;
  int c = idx/196, rem = idx%196, i = rem/14, jx = rem%14;
  float acc = b[c];
  for (int ic=0; ic<128; ++ic){
    const float* xc = x1 + (size_t)ic*900;
    const float* wc = w + ((size_t)c*128 + ic)*16;
#pragma unroll
    for (int ky=0; ky<4; ++ky)
#pragma unroll
      for (int kx=0; kx<4; ++kx)
        acc += xc[(i*2+ky)*30 + (jx*2+kx)] * wc[ky*4+kx];
  }
  y[idx] = fmaxf(acc, 0.0f);
}

__global__ __launch_bounds__(256) void conv3_kernel(
    const float* __restrict__ x2, const float* __restrict__ w, const float* __restrict__ b,
    float* __restrict__ y)
{
  int idx = blockIdx.x*256 + threadIdx.x;
  if (idx >= 64*6*6) return;
  int c = idx/36, rem = idx%36, i = rem/6, jx = rem%6;
  float acc = b[c];
  for (int ic=0; ic<64; ++ic){
    const float* xc = x2 + (size_t)ic*196;
    const float* wc = w + ((size_t)c*64 + ic)*16;
#pragma unroll
    for (int ky=0; ky<4; ++ky)
#pragma unroll
      for (int kx=0; kx<4; ++kx)
        acc += xc[(i*2+ky)*14 + (jx*2+kx)] * wc[ky*4+kx];
  }
  y[idx] = fmaxf(acc, 0.0f);
}

// ---------------- image embedding (32 blocks x 8 rows, coalesced) --------------
__global__ __launch_bounds__(256) void imgemb_kernel(
    const float* __restrict__ x_img, const float* __restrict__ img_w, const float* __restrict__ img_b,
    const float* __restrict__ hf, const float* __restrict__ hb, float* __restrict__ ak_in)
{
  int u = threadIdx.x;
  int r = blockIdx.x*8 + (u>>5);
  int lane = u & 31;
  const float* wr = img_w + (size_t)r*2304;
  float acc = 0.0f;
  for (int k=lane; k<2304; k+=32) acc += wr[k]*x_img[k];
#pragma unroll
  for (int m=16; m; m>>=1) acc += __shfl_xor(acc, m, 64);
  if (lane == 0) ak_in[512+r] = img_b[r] + acc;
  if (blockIdx.x == 0){
    ak_in[u]     = hf[(size_t)767*256+u];  // curr_rep fwd half
    ak_in[256+u] = hb[(size_t)767*256+u];  // curr_rep bwd half (rb[P])
  }
}

// ---------------- attention (block 0 = prev, block 1 = next) -------------------
__global__ __launch_bounds__(512) void attend_kernel(
    const float* __restrict__ ak_in_g,
    const float* __restrict__ akp_w, const float* __restrict__ akp_b,
    const float* __restrict__ akn_w, const float* __restrict__ akn_b,
    const float* __restrict__ bil_p_w, const float* __restrict__ bil_p_b,
    const float* __restrict__ bil_n_w, const float* __restrict__ bil_n_b,
    const float* __restrict__ hf, const float* __restrict__ hb,
    float* __restrict__ prev_sum, float* __restrict__ next_sum)
{
  int blk = blockIdx.x;
  const float* akw = blk? akn_w : akp_w;
  const float* akb = blk? akn_b : akp_b;
  const float* bw  = blk? bil_n_w : bil_p_w;
  float bb         = blk? bil_n_b[0] : bil_p_b[0];
  float* outp      = blk? next_sum : prev_sum;

  int u = threadIdx.x;
  __shared__ __align__(16) float ak[768];
  __shared__ __align__(16) float kk[256];
  __shared__ __align__(16) float q[512];
  __shared__ float s[512], red[512];

  for (int i=u; i<768; i+=512) ak[i] = ak_in_g[i];
  __syncthreads();

  if (u < 256){
    float a0=0.f,a1=0.f,a2=0.f,a3=0.f;
    const float4* wr = (const float4*)(akw + (size_t)u*768);
    const float4* av = (const float4*)ak;
    for (int m=0; m<192; ++m){
      float4 w = wr[m], aa = av[m];
      a0 += w.x*aa.x; a1 += w.y*aa.y; a2 += w.z*aa.z; a3 += w.w*aa.w;
    }
    kk[u] = akb[u] + ((a0+a1)+(a2+a3));
  }
  __syncthreads();

  { // q = k @ bw[0]   (coalesced: lane u reads column u)
    float acc = 0.0f;
    for (int m=0; m<256; ++m) acc += kk[m]*bw[(size_t)m*512 + u];
    q[u] = acc;
  }
  __syncthreads();

  { // scores: s[i] = q . rep[i] + bb
    int i = u;
    const float4* repf = (const float4*)(hf + (size_t)(blk? (768+i) : i)*256);
    const float4* repb = (const float4*)(hb + (size_t)(blk? (511-i) : (1279-i))*256);
    const float4* qf = (const float4*)q;
    float a0=0.f,a1=0.f;
    for (int v=0; v<64; ++v){
      float4 qq = qf[v],  rr = repf[v];
      a0 += qq.x*rr.x + qq.y*rr.y + qq.z*rr.z + qq.w*rr.w;
      float4 q2 = qf[64+v], r2 = repb[v];
      a1 += q2.x*r2.x + q2.y*r2.y + q2.z*r2.z + q2.w*r2.w;
    }
    s[u] = bb + a0 + a1;
  }
  __syncthreads();

  // softmax over 512
  red[u] = s[u]; __syncthreads();
  for (int st=256; st>0; st>>=1){ if (u<st) red[u]=fmaxf(red[u],red[u+st]); __syncthreads(); }
  float mx = red[0]; __syncthreads();
  float ex = __expf(s[u]-mx);
  red[u] = ex; __syncthreads();
  for (int st=256; st>0; st>>=1){ if (u<st) red[u]+=red[u+st]; __syncthreads(); }
  float inv = 1.0f/red[0]; __syncthreads();
  s[u] = ex*inv;
  __syncthreads();

  // weighted sum over rows (coalesced: lane reads column u)
  float o = 0.0f;
  if (u < 256){
    for (int r=0; r<512; ++r){
      const float* rf = hf + (size_t)(blk? (768+r) : r)*256;
      o += s[r]*rf[u];
    }
    outp[u] = o;
  } else {
    int v = u-256;
    for (int r=0; r<512; ++r){
      const float* rb = hb + (size_t)(blk? (511-r) : (1279-r))*256;
      o += s[r]*rb[v];
    }
    outp[u] = o;
  }
}

// ---------------- head stage A: pred/nred -> gate ------------------------------
__global__ __launch_bounds__(256) void head_a_kernel(
    const float* __restrict__ psum, const float* __restrict__ nsum,
    const float* __restrict__ akin,
    const float* __restrict__ pred_w, const float* __restrict__ pred_b,
    const float* __restrict__ nred_w, const float* __restrict__ nred_b,
    const float* __restrict__ gate_w, const float* __restrict__ gate_b,
    float* __restrict__ gate_out)
{
  int u = threadIdx.x;
  __shared__ __align__(16) float ps[512], ns[512], cr[512];
  __shared__ float pg[64], ng[64];
  for (int i=u; i<512; i+=256){ ps[i]=psum[i]; ns[i]=nsum[i]; cr[i]=akin[i]; }
  __syncthreads();

  if (u < 64){
    float a = pred_b[u];
    const float* wr = pred_w + (size_t)u*512;
    for (int k=0;k<512;++k) a += ps[k]*wr[k];
    pg[u] = a;
  } else if (u < 128){
    int t = u-64;
    float a = nred_b[t];
    const float* wr = nred_w + (size_t)t*512;
    for (int k=0;k<512;++k) a += ns[k]*wr[k];
    ng[t] = a;
  }
  __syncthreads();

  if (u < 64){
    float a = gate_b[u];
    const float* wr = gate_w + (size_t)u*640;
    for (int k=0;k<512;++k) a += cr[k]*wr[k];
    for (int k=0;k<64;++k)  a += pg[k]*wr[512+k];
    for (int k=0;k<64;++k)  a += ng[k]*wr[576+k];
    gate_out[u] = sigf(a);
  }
}

// ---------------- lin: feat = relu(lin_w @ (x_img*gate) + lin_b) ---------------
__global__ __launch_bounds__(256) void lin_kernel(
    const float* __restrict__ x_img, const float* __restrict__ gate,
    const float* __restrict__ lin_w, const float* __restrict__ lin_b,
    float* __restrict__ feat)
{
  int u = threadIdx.x;
  __shared__ __align__(16) float xg[2304];
  for (int i=u; i<2304; i+=256) xg[i] = x_img[i]*gate[i/36];
  __syncthreads();

  int r = blockIdx.x*8 + (u>>5);
  int lane = u & 31;
  const float* wr = lin_w + (size_t)r*2304;
  float acc = 0.0f;
  for (int k=lane; k<2304; k+=32) acc += wr[k]*xg[k];
#pragma unroll
  for (int m=16; m; m>>=1) acc += __shfl_xor(acc, m, 64);
  if (lane == 0) feat[r] = fmaxf(lin_b[r] + acc, 0.0f);
}

// ---------------- lstm gates: g[1024] --------------------------------------
__global__ __launch_bounds__(256) void lstm_kernel(
    const float* __restrict__ feat, const float* __restrict__ hx,
    const float* __restrict__ wih, const float* __restrict__ whh,
    const float* __restrict__ bih, const float* __restrict__ bhh,
    float* __restrict__ g)
{
  int u = threadIdx.x;
  __shared__ __align__(16) float fs[256], hs[256];
  fs[u] = feat[u]; hs[u] = hx[u];
  __syncthreads();
  int row = blockIdx.x*256 + u;
  float a0=0.f, a1=0.f;
  const float4* w1 = (const float4*)(wih + (size_t)row*256);
  const float4* w2 = (const float4*)(whh + (size_t)row*256);
  const float4* fv = (const float4*)fs;
  const float4* hv = (const float4*)hs;
  for (int k=0;k<64;++k){
    float4 wa = w1[k], fa = fv[k];
    a0 += wa.x*fa.x + wa.y*fa.y + wa.z*fa.z + wa.w*fa.w;
    float4 wb = w2[k], ha = hv[k];
    a1 += wb.x*ha.x + wb.y*ha.y + wb.z*ha.z + wb.w*ha.w;
  }
  g[row] = bih[row] + bhh[row] + a0 + a1;
}

// ---------------- final: LSTM elementwise + crit/act ---------------------------
__global__ __launch_bounds__(320) void final_kernel(
    const float* __restrict__ g, const float* __restrict__ cx,
    const int* __restrict__ tx, const float* __restrict__ time_emb,
    const float* __restrict__ crit_w, const float* __restrict__ crit_b,
    const float* __restrict__ act_w,  const float* __restrict__ act_b,
    float* __restrict__ out)
{
  int u = threadIdx.x;
  __shared__ float z[320];
  if (u < 256){
    float ii=g[u], ff=g[256+u], gg=g[512+u], oo=g[768+u];
    float c2 = sigf(ff)*cx[u] + sigf(ii)*tanhfast(gg);
    float h2 = sigf(oo)*tanhfast(c2);
    out[5+u]   = h2;
    out[261+u] = c2;
    z[u] = h2;
  } else if (u < 288){
    z[u] = time_emb[(size_t)tx[0]*32 + (u-256)];
  }
  __syncthreads();
  int row = u >> 6, lane = u & 63;
  const float* wv = (row==0)? crit_w : (act_w + (size_t)(row-1)*288);
  float acc = 0.0f;
  for (int k=lane; k<288; k+=64) acc += wv[k]*z[k];
#pragma unroll
  for (int m=32; m; m>>=1) acc += __shfl_xor(acc, m, 64);
  if (lane == 0){
    float b = (row==0)? crit_b[0] : act_b[row-1];
    out[row] = acc + b;   // out[0]=crit, out[1..4]=act
  }
}

// ---------------------------------------------------------------------------
extern "C" void kernel_launch(void* const* d_in, const int* in_sizes, int n_in,
                              void* d_out, int out_size, void* d_ws, size_t ws_size,
                              hipStream_t stream)
{
  const float* x        = (const float*)d_in[0];
  const float* hx       = (const float*)d_in[1];
  const float* cx       = (const float*)d_in[2];
  const int*  prev      = (const int*)d_in[3];
  const int*  curr      = (const int*)d_in[4];
  const int*  nxt       = (const int*)d_in[5];
  const int*  tx        = (const int*)d_in[6];
  const float* emb      = (const float*)d_in[7];
  const float* gru_wih  = (const float*)d_in[8];
  const float* gru_whh  = (const float*)d_in[9];
  const float* gru_bih  = (const float*)d_in[10];
  const float* gru_bhh  = (const float*)d_in[11];
  const float* conv1_w  = (const float*)d_in[12];
  const float* conv1_b  = (const float*)d_in[13];
  const float* conv2_w  = (const float*)d_in[14];
  const float* conv2_b  = (const float*)d_in[15];
  const float* conv3_w  = (const float*)d_in[16];
  const float* conv3_b  = (const float*)d_in[17];
  const float* img_w    = (const float*)d_in[18];
  const float* img_b    = (const float*)d_in[19];
  const float* akp_w    = (const float*)d_in[20];
  const float* akp_b    = (const float*)d_in[21];
  const float* akn_w    = (const float*)d_in[22];
  const float* akn_b    = (const float*)d_in[23];
  const float* bil_p_w  = (const float*)d_in[24];
  const float* bil_p_b  = (const float*)d_in[25];
  const float* bil_n_w  = (const float*)d_in[26];
  const float* bil_n_b  = (const float*)d_in[27];
  const float* pred_w   = (const float*)d_in[28];
  const float* pred_b   = (const float*)d_in[29];
  const float* nred_w   = (const float*)d_in[30];
  const float* nred_b   = (const float*)d_in[31];
  const float* gate_w   = (const float*)d_in[32];
  const float* gate_b   = (const float*)d_in[33];
  const float* lin_w    = (const float*)d_in[34];
  const float* lin_b    = (const float*)d_in[35];
  const float* lstm_wih = (const float*)d_in[36];
  const float* lstm_whh = (const float*)d_in[37];
  const float* lstm_bih = (const float*)d_in[38];
  const float* lstm_bhh = (const float*)d_in[39];
  const float* time_emb = (const float*)d_in[40];
  const float* crit_w   = (const float*)d_in[41];
  const float* crit_b   = (const float*)d_in[42];
  const float* act_w    = (const float*)d_in[43];
  const float* act_b    = (const float*)d_in[44];

  float* ws = (float*)d_ws;
  float* gi    = ws + GI_OFF;
  float* hf    = ws + HF_OFF;
  float* hb    = ws + HB_OFF;
  float* x1    = ws + X1_OFF;
  float* x2    = ws + X2_OFF;
  float* ximg  = ws + XIMG_OFF;
  float* akin  = ws + AKIN_OFF;
  float* psum  = ws + PSUM_OFF;
  float* nsum  = ws + NSUM_OFF;
  float* gatev = ws + GATE_OFF;
  float* featv = ws + FEAT_OFF;
  float* gvec  = ws + G_OFF;

  float* out = (float*)d_out;

  gi_kernel      <<<160, 256, 0, stream>>>(emb, gru_wih, gru_bih, prev, curr, nxt, gi);
  gru_scan_kernel<<<6,   256, 0, stream>>>(gru_whh, gru_bhh, gi, hf, hb);
  conv1_kernel   <<<450, 256, 0, stream>>>(x, conv1_w, conv1_b, x1);
  conv2_kernel   <<<49,  256, 0, stream>>>(x1, conv2_w, conv2_b, x2);
  conv3_kernel   <<<9,   256, 0, stream>>>(x2, conv3_w, conv3_b, ximg);
  imgemb_kernel  <<<32,  256, 0, stream>>>(ximg, img_w, img_b, hf, hb, akin);
  attend_kernel  <<<2,   512, 0, stream>>>(akin, akp_w, akp_b, akn_w, akn_b,
                                           bil_p_w, bil_p_b, bil_n_w, bil_n_b,
                                           hf, hb, psum, nsum);
  head_a_kernel  <<<1,   256, 0, stream>>>(psum, nsum, akin,
                                           pred_w, pred_b, nred_w, nred_b,
                                           gate_w, gate_b, gatev);
  lin_kernel     <<<32,  256, 0, stream>>>(ximg, gatev, lin_w, lin_b, featv);
  lstm_kernel    <<<4,   256, 0, stream>>>(featv, hx, lstm_wih, lstm_whh,
                                           lstm_bih, lstm_bhh, gvec);
  final_kernel   <<<1,   320, 0, stream>>>(gvec, cx, tx, time_emb,
                                           crit_w, crit_b, act_w, act_b, out);
}

// Round 6
// 950.862 us; speedup vs baseline: 11.5202x; 1.1546x over previous
//
#include <hip/hip_runtime.h>
#include <hip/hip_bf16.h>

typedef unsigned int u32;
typedef _Float16 f16x8 __attribute__((ext_vector_type(8)));
typedef float f32x4 __attribute__((ext_vector_type(4)));

__device__ __forceinline__ float sigf(float x){ return 1.0f/(1.0f + __expf(-x)); }
__device__ __forceinline__ float tanhfast(float x){
  float xc = fminf(fmaxf(x, -15.0f), 15.0f);
  float e = __expf(2.0f*xc);
  return (e - 1.0f)/(e + 1.0f);
}

// ---------------------------------------------------------------------------
// ws layout (float offsets)
// ---------------------------------------------------------------------------
#define GI_OFF   0
#define GI_SZ    (2560*768)
#define HF_OFF   (GI_OFF + GI_SZ)
#define HF_SZ    (1280*256)
#define HB_OFF   (HF_OFF + HF_SZ)
#define X1_OFF   (HB_OFF + HF_SZ)
#define X1_SZ    (128*30*30)
#define X2_OFF   (X1_OFF + X1_SZ)
#define X2_SZ    (64*14*14)
#define XIMG_OFF (X2_OFF + X2_SZ)
#define XIMG_SZ  (64*6*6)
#define AKIN_OFF (XIMG_OFF + XIMG_SZ)
#define PSUM_OFF (AKIN_OFF + 768)
#define NSUM_OFF (PSUM_OFF + 512)
#define GATE_OFF (NSUM_OFF + 512)
#define FEAT_OFF (GATE_OFF + 64)
#define G_OFF    (FEAT_OFF + 256)

// ---------------- gi precompute: gi[row][768] = emb[tok] @ wih[j].T + bih[j] ----
__global__ __launch_bounds__(256) void gi_kernel(
    const float* __restrict__ emb, const float* __restrict__ wih_all,
    const float* __restrict__ bih_all,
    const int* __restrict__ prev, const int* __restrict__ curr, const int* __restrict__ nxt,
    float* __restrict__ gi_all)
{
  const int offs[7] = {0,512,768,1280,1792,2048,2560};
  int row0 = blockIdx.x * 16;
  int j = 0;
  while (row0 >= offs[j+1]) ++j;
  int t0 = row0 - offs[j];
  int sel = j % 3;
  const int* inst = (sel==0)? prev : (sel==1)? curr : nxt;

  __shared__ __align__(16) float e[16][32];
  int u = threadIdx.x;
  for (int idx=u; idx<512; idx+=256){
    int r = idx >> 5, k = idx & 31;
    e[r][k] = emb[(size_t)inst[t0+r]*32 + k];
  }
  __syncthreads();

  const float* wih = wih_all + (size_t)j*768*32;
  const float* bih = bih_all + (size_t)j*768;
  for (int g3=0; g3<3; ++g3){
    int o = g3*256 + u;
    float bb = bih[o];
    float acc[16];
#pragma unroll
    for (int r=0;r<16;++r) acc[r]=bb;
    const float* wr = wih + (size_t)o*32;
#pragma unroll
    for (int k=0;k<32;++k){
      float w = wr[k];
#pragma unroll
      for (int r=0;r<16;++r) acc[r] += w * e[r][k];
    }
    for (int r=0;r<16;++r) gi_all[(size_t)(row0+r)*768 + o] = acc[r];
  }
}

// ---------------- GRU sequential scan: 6 blocks, one per GRU -------------------
// 512 threads = 8 waves, PINNED at 2 waves/EU (reg budget 256/thread, no
// occupancy incentive for the allocator to spill). Wave w owns 6 row-tiles:
// af[6][8] = 192 VGPRs + acc 24 + scaffold ~25 = ~240 <= 256.
__global__
__attribute__((amdgpu_flat_work_group_size(512,512)))
__attribute__((amdgpu_waves_per_eu(2,2)))
void gru_scan_kernel(
    const float* __restrict__ whh_all, const float* __restrict__ bhh_all,
    const float* __restrict__ gi_all, float* __restrict__ hf, float* __restrict__ hb)
{
  const int lens[6] = {512,256,512,512,256,512};
  const int offs[6] = {0,512,768,1280,1792,2048};
  int j = blockIdx.x;
  int u = threadIdx.x;
  int len = lens[j];
  const float* gi = gi_all + (size_t)offs[j]*768;
  float* outp = ((j<3)? hf : hb) + (size_t)offs[j%3]*256;

  int w    = u >> 6;   // wave 0..7
  int l    = u & 63;
  int arow = l & 15;   // A row within tile / D col
  int kgrp = l >> 4;   // k-group 0..3

  // A fragments: af[i][kt] = W[16*(w*6+i)+arow][32*kt+8*kgrp .. +8) as f16
  f16x8 af[6][8];
  {
    const float* Wj = whh_all + (size_t)j*768*256;
#pragma unroll
    for (int i=0;i<6;++i){
      const float* wrow = Wj + (size_t)(16*(w*6+i) + arow)*256;
#pragma unroll
      for (int kt=0;kt<8;++kt){
        const float4* p = (const float4*)(wrow + 32*kt + 8*kgrp);
        float4 c0 = p[0], c1 = p[1];
        f16x8 v;
        v[0]=(_Float16)c0.x; v[1]=(_Float16)c0.y; v[2]=(_Float16)c0.z; v[3]=(_Float16)c0.w;
        v[4]=(_Float16)c1.x; v[5]=(_Float16)c1.y; v[6]=(_Float16)c1.z; v[7]=(_Float16)c1.w;
        af[i][kt] = v;
      }
    }
  }

  float bh0=0.f, bh1=0.f, bh2=0.f, hprev=0.f;
  if (u < 256){
    bh0 = bhh_all[j*768 + u];
    bh1 = bhh_all[j*768 + 256 + u];
    bh2 = bhh_all[j*768 + 512 + u];
  }

  __shared__ __align__(16) _Float16 h16[256];
  __shared__ __align__(16) float gacc[768];
  if (u < 256) h16[u] = (_Float16)0.0f;
  __syncthreads();

  for (int t=0; t<len; ++t){
    // delayed store of previous h (drains during MFMA phase, not at a barrier)
    float gr=0.f, gz=0.f, gn=0.f;
    if (u < 256){
      if (t > 0) outp[(size_t)(t-1)*256 + u] = hprev;
      const float* git = gi + (size_t)t*768;
      gr = git[u]; gz = git[256+u]; gn = git[512+u];
    }

    // W @ h via MFMA (6 tiles, 6 independent acc chains)
    f32x4 acc[6];
#pragma unroll
    for (int i=0;i<6;++i){ f32x4 zz = {0.f,0.f,0.f,0.f}; acc[i] = zz; }
#pragma unroll
    for (int kt=0; kt<8; ++kt){
      f16x8 bfr = *(const f16x8*)(h16 + 32*kt + 8*kgrp);
#pragma unroll
      for (int i=0;i<6;++i)
        acc[i] = __builtin_amdgcn_mfma_f32_16x16x32_f16(af[i][kt], bfr, acc[i], 0, 0, 0);
    }
    if (arow == 0){
#pragma unroll
      for (int i=0;i<6;++i){
        float4 v; v.x=acc[i][0]; v.y=acc[i][1]; v.z=acc[i][2]; v.w=acc[i][3];
        *(float4*)&gacc[16*(w*6+i) + 4*kgrp] = v;
      }
    }
    __syncthreads();

    if (u < 256){
      float r  = sigf(gr + bh0 + gacc[u]);
      float z  = sigf(gz + bh1 + gacc[256+u]);
      float n  = tanhfast(gn + bh2 + r*gacc[512+u]);
      float h2 = (1.0f - z)*n + z*hprev;
      h16[u] = (_Float16)h2;
      hprev = h2;
    }
    __syncthreads();
  }
  if (u < 256) outp[(size_t)(len-1)*256 + u] = hprev;
}

// ---------------- convs (direct, one thread per output) ------------------------
__global__ __launch_bounds__(256) void conv1_kernel(
    const float* __restrict__ x, const float* __restrict__ w, const float* __restrict__ b,
    float* __restrict__ y)
{
  int idx = blockIdx.x*256 + threadIdx.x;
  if (idx >= 128*30*30) return;
  int c = idx/900, rem = idx%900, i = rem/30, jx = rem%30;
  float acc = b[c];
  const float* wc = w + (size_t)c*3*8*8;
  for (int ic=0; ic<3; ++ic)
    for (int ky=0; ky<8; ++ky){
      const float* xrow = x + ((size_t)ic*124 + (i*4+ky))*124 + jx*4;
      const float* wrow = wc + (ic*8+ky)*8;
#pragma unroll
      for (int kx=0; kx<8; ++kx) acc += xrow[kx] * wrow[kx];
    }
  y[idx] = fmaxf(acc, 0.0f);
}

__global__ __launch_bounds__(256) void conv2_kernel(
    const float* __restrict__ x1, const float* __restrict__ w, const float* __restrict__ b,
    float* __restrict__ y)
{
  int idx = blockIdx.x*256 + threadIdx.x;
  if (idx >= 64*14*14) return;
  int c = idx/196, rem = idx%196, i = rem/14, jx = rem%14;
  float acc = b[c];
  for (int ic=0; ic<128; ++ic){
    const float* xc = x1 + (size_t)ic*900;
    const float* wc = w + ((size_t)c*128 + ic)*16;
#pragma unroll
    for (int ky=0; ky<4; ++ky)
#pragma unroll
      for (int kx=0; kx<4; ++kx)
        acc += xc[(i*2+ky)*30 + (jx*2+kx)] * wc[ky*4+kx];
  }
  y[idx] = fmaxf(acc, 0.0f);
}

__global__ __launch_bounds__(256) void conv3_kernel(
    const float* __restrict__ x2, const float* __restrict__ w, const float* __restrict__ b,
    float* __restrict__ y)
{
  int idx = blockIdx.x*256 + threadIdx.x;
  if (idx >= 64*6*6) return;
  int c = idx/36, rem = idx%36, i = rem/6, jx = rem%6;
  float acc = b[c];
  for (int ic=0; ic<64; ++ic){
    const float* xc = x2 + (size_t)ic*196;
    const float* wc = w + ((size_t)c*64 + ic)*16;
#pragma unroll
    for (int ky=0; ky<4; ++ky)
#pragma unroll
      for (int kx=0; kx<4; ++kx)
        acc += xc[(i*2+ky)*14 + (jx*2+kx)] * wc[ky*4+kx];
  }
  y[idx] = fmaxf(acc, 0.0f);
}

// ---------------- image embedding (32 blocks x 8 rows, coalesced) --------------
__global__ __launch_bounds__(256) void imgemb_kernel(
    const float* __restrict__ x_img, const float* __restrict__ img_w, const float* __restrict__ img_b,
    const float* __restrict__ hf, const float* __restrict__ hb, float* __restrict__ ak_in)
{
  int u = threadIdx.x;
  int r = blockIdx.x*8 + (u>>5);
  int lane = u & 31;
  const float* wr = img_w + (size_t)r*2304;
  float acc = 0.0f;
  for (int k=lane; k<2304; k+=32) acc += wr[k]*x_img[k];
#pragma unroll
  for (int m=16; m; m>>=1) acc += __shfl_xor(acc, m, 64);
  if (lane == 0) ak_in[512+r] = img_b[r] + acc;
  if (blockIdx.x == 0){
    ak_in[u]     = hf[(size_t)767*256+u];  // curr_rep fwd half
    ak_in[256+u] = hb[(size_t)767*256+u];  // curr_rep bwd half (rb[P])
  }
}

// ---------------- attention (block 0 = prev, block 1 = next) -------------------
__global__ __launch_bounds__(512) void attend_kernel(
    const float* __restrict__ ak_in_g,
    const float* __restrict__ akp_w, const float* __restrict__ akp_b,
    const float* __restrict__ akn_w, const float* __restrict__ akn_b,
    const float* __restrict__ bil_p_w, const float* __restrict__ bil_p_b,
    const float* __restrict__ bil_n_w, const float* __restrict__ bil_n_b,
    const float* __restrict__ hf, const float* __restrict__ hb,
    float* __restrict__ prev_sum, float* __restrict__ next_sum)
{
  int blk = blockIdx.x;
  const float* akw = blk? akn_w : akp_w;
  const float* akb = blk? akn_b : akp_b;
  const float* bw  = blk? bil_n_w : bil_p_w;
  float bb         = blk? bil_n_b[0] : bil_p_b[0];
  float* outp      = blk? next_sum : prev_sum;

  int u = threadIdx.x;
  __shared__ __align__(16) float ak[768];
  __shared__ __align__(16) float kk[256];
  __shared__ __align__(16) float q[512];
  __shared__ float s[512], red[512];

  for (int i=u; i<768; i+=512) ak[i] = ak_in_g[i];
  __syncthreads();

  if (u < 256){
    float a0=0.f,a1=0.f,a2=0.f,a3=0.f;
    const float4* wr = (const float4*)(akw + (size_t)u*768);
    const float4* av = (const float4*)ak;
    for (int m=0; m<192; ++m){
      float4 w = wr[m], aa = av[m];
      a0 += w.x*aa.x; a1 += w.y*aa.y; a2 += w.z*aa.z; a3 += w.w*aa.w;
    }
    kk[u] = akb[u] + ((a0+a1)+(a2+a3));
  }
  __syncthreads();

  { // q = k @ bw[0]   (coalesced: lane u reads column u)
    float acc = 0.0f;
    for (int m=0; m<256; ++m) acc += kk[m]*bw[(size_t)m*512 + u];
    q[u] = acc;
  }
  __syncthreads();

  { // scores: s[i] = q . rep[i] + bb
    int i = u;
    const float4* repf = (const float4*)(hf + (size_t)(blk? (768+i) : i)*256);
    const float4* repb = (const float4*)(hb + (size_t)(blk? (511-i) : (1279-i))*256);
    const float4* qf = (const float4*)q;
    float a0=0.f,a1=0.f;
    for (int v=0; v<64; ++v){
      float4 qq = qf[v],  rr = repf[v];
      a0 += qq.x*rr.x + qq.y*rr.y + qq.z*rr.z + qq.w*rr.w;
      float4 q2 = qf[64+v], r2 = repb[v];
      a1 += q2.x*r2.x + q2.y*r2.y + q2.z*r2.z + q2.w*r2.w;
    }
    s[u] = bb + a0 + a1;
  }
  __syncthreads();

  // softmax over 512
  red[u] = s[u]; __syncthreads();
  for (int st=256; st>0; st>>=1){ if (u<st) red[u]=fmaxf(red[u],red[u+st]); __syncthreads(); }
  float mx = red[0]; __syncthreads();
  float ex = __expf(s[u]-mx);
  red[u] = ex; __syncthreads();
  for (int st=256; st>0; st>>=1){ if (u<st) red[u]+=red[u+st]; __syncthreads(); }
  float inv = 1.0f/red[0]; __syncthreads();
  s[u] = ex*inv;
  __syncthreads();

  // weighted sum over rows (coalesced: lane reads column u)
  float o = 0.0f;
  if (u < 256){
    for (int r=0; r<512; ++r){
      const float* rf = hf + (size_t)(blk? (768+r) : r)*256;
      o += s[r]*rf[u];
    }
    outp[u] = o;
  } else {
    int v = u-256;
    for (int r=0; r<512; ++r){
      const float* rb = hb + (size_t)(blk? (511-r) : (1279-r))*256;
      o += s[r]*rb[v];
    }
    outp[u] = o;
  }
}

// ---------------- head stage A: pred/nred -> gate ------------------------------
__global__ __launch_bounds__(256) void head_a_kernel(
    const float* __restrict__ psum, const float* __restrict__ nsum,
    const float* __restrict__ akin,
    const float* __restrict__ pred_w, const float* __restrict__ pred_b,
    const float* __restrict__ nred_w, const float* __restrict__ nred_b,
    const float* __restrict__ gate_w, const float* __restrict__ gate_b,
    float* __restrict__ gate_out)
{
  int u = threadIdx.x;
  __shared__ __align__(16) float ps[512], ns[512], cr[512];
  __shared__ float pg[64], ng[64];
  for (int i=u; i<512; i+=256){ ps[i]=psum[i]; ns[i]=nsum[i]; cr[i]=akin[i]; }
  __syncthreads();

  if (u < 64){
    float a = pred_b[u];
    const float* wr = pred_w + (size_t)u*512;
    for (int k=0;k<512;++k) a += ps[k]*wr[k];
    pg[u] = a;
  } else if (u < 128){
    int t = u-64;
    float a = nred_b[t];
    const float* wr = nred_w + (size_t)t*512;
    for (int k=0;k<512;++k) a += ns[k]*wr[k];
    ng[t] = a;
  }
  __syncthreads();

  if (u < 64){
    float a = gate_b[u];
    const float* wr = gate_w + (size_t)u*640;
    for (int k=0;k<512;++k) a += cr[k]*wr[k];
    for (int k=0;k<64;++k)  a += pg[k]*wr[512+k];
    for (int k=0;k<64;++k)  a += ng[k]*wr[576+k];
    gate_out[u] = sigf(a);
  }
}

// ---------------- lin: feat = relu(lin_w @ (x_img*gate) + lin_b) ---------------
__global__ __launch_bounds__(256) void lin_kernel(
    const float* __restrict__ x_img, const float* __restrict__ gate,
    const float* __restrict__ lin_w, const float* __restrict__ lin_b,
    float* __restrict__ feat)
{
  int u = threadIdx.x;
  __shared__ __align__(16) float xg[2304];
  for (int i=u; i<2304; i+=256) xg[i] = x_img[i]*gate[i/36];
  __syncthreads();

  int r = blockIdx.x*8 + (u>>5);
  int lane = u & 31;
  const float* wr = lin_w + (size_t)r*2304;
  float acc = 0.0f;
  for (int k=lane; k<2304; k+=32) acc += wr[k]*xg[k];
#pragma unroll
  for (int m=16; m; m>>=1) acc += __shfl_xor(acc, m, 64);
  if (lane == 0) feat[r] = fmaxf(lin_b[r] + acc, 0.0f);
}

// ---------------- lstm gates: g[1024] --------------------------------------
__global__ __launch_bounds__(256) void lstm_kernel(
    const float* __restrict__ feat, const float* __restrict__ hx,
    const float* __restrict__ wih, const float* __restrict__ whh,
    const float* __restrict__ bih, const float* __restrict__ bhh,
    float* __restrict__ g)
{
  int u = threadIdx.x;
  __shared__ __align__(16) float fs[256], hs[256];
  fs[u] = feat[u]; hs[u] = hx[u];
  __syncthreads();
  int row = blockIdx.x*256 + u;
  float a0=0.f, a1=0.f;
  const float4* w1 = (const float4*)(wih + (size_t)row*256);
  const float4* w2 = (const float4*)(whh + (size_t)row*256);
  const float4* fv = (const float4*)fs;
  const float4* hv = (const float4*)hs;
  for (int k=0;k<64;++k){
    float4 wa = w1[k], fa = fv[k];
    a0 += wa.x*fa.x + wa.y*fa.y + wa.z*fa.z + wa.w*fa.w;
    float4 wb = w2[k], ha = hv[k];
    a1 += wb.x*ha.x + wb.y*ha.y + wb.z*ha.z + wb.w*ha.w;
  }
  g[row] = bih[row] + bhh[row] + a0 + a1;
}

// ---------------- final: LSTM elementwise + crit/act ---------------------------
__global__ __launch_bounds__(320) void final_kernel(
    const float* __restrict__ g, const float* __restrict__ cx,
    const int* __restrict__ tx, const float* __restrict__ time_emb,
    const float* __restrict__ crit_w, const float* __restrict__ crit_b,
    const float* __restrict__ act_w,  const float* __restrict__ act_b,
    float* __restrict__ out)
{
  int u = threadIdx.x;
  __shared__ float z[320];
  if (u < 256){
    float ii=g[u], ff=g[256+u], gg=g[512+u], oo=g[768+u];
    float c2 = sigf(ff)*cx[u] + sigf(ii)*tanhfast(gg);
    float h2 = sigf(oo)*tanhfast(c2);
    out[5+u]   = h2;
    out[261+u] = c2;
    z[u] = h2;
  } else if (u < 288){
    z[u] = time_emb[(size_t)tx[0]*32 + (u-256)];
  }
  __syncthreads();
  int row = u >> 6, lane = u & 63;
  const float* wv = (row==0)? crit_w : (act_w + (size_t)(row-1)*288);
  float acc = 0.0f;
  for (int k=lane; k<288; k+=64) acc += wv[k]*z[k];
#pragma unroll
  for (int m=32; m; m>>=1) acc += __shfl_xor(acc, m, 64);
  if (lane == 0){
    float b = (row==0)? crit_b[0] : act_b[row-1];
    out[row] = acc + b;   // out[0]=crit, out[1..4]=act
  }
}

// ---------------------------------------------------------------------------
extern "C" void kernel_launch(void* const* d_in, const int* in_sizes, int n_in,
                              void* d_out, int out_size, void* d_ws, size_t ws_size,
                              hipStream_t stream)
{
  const float* x        = (const float*)d_in[0];
  const float* hx       = (const float*)d_in[1];
  const float* cx       = (const float*)d_in[2];
  const int*  prev      = (const int*)d_in[3];
  const int*  curr      = (const int*)d_in[4];
  const int*  nxt       = (const int*)d_in[5];
  const int*  tx        = (const int*)d_in[6];
  const float* emb      = (const float*)d_in[7];
  const float* gru_wih  = (const float*)d_in[8];
  const float* gru_whh  = (const float*)d_in[9];
  const float* gru_bih  = (const float*)d_in[10];
  const float* gru_bhh  = (const float*)d_in[11];
  const float* conv1_w  = (const float*)d_in[12];
  const float* conv1_b  = (const float*)d_in[13];
  const float* conv2_w  = (const float*)d_in[14];
  const float* conv2_b  = (const float*)d_in[15];
  const float* conv3_w  = (const float*)d_in[16];
  const float* conv3_b  = (const float*)d_in[17];
  const float* img_w    = (const float*)d_in[18];
  const float* img_b    = (const float*)d_in[19];
  const float* akp_w    = (const float*)d_in[20];
  const float* akp_b    = (const float*)d_in[21];
  const float* akn_w    = (const float*)d_in[22];
  const float* akn_b    = (const float*)d_in[23];
  const float* bil_p_w  = (const float*)d_in[24];
  const float* bil_p_b  = (const float*)d_in[25];
  const float* bil_n_w  = (const float*)d_in[26];
  const float* bil_n_b  = (const float*)d_in[27];
  const float* pred_w   = (const float*)d_in[28];
  const float* pred_b   = (const float*)d_in[29];
  const float* nred_w   = (const float*)d_in[30];
  const float* nred_b   = (const float*)d_in[31];
  const float* gate_w   = (const float*)d_in[32];
  const float* gate_b   = (const float*)d_in[33];
  const float* lin_w    = (const float*)d_in[34];
  const float* lin_b    = (const float*)d_in[35];
  const float* lstm_wih = (const float*)d_in[36];
  const float* lstm_whh = (const float*)d_in[37];
  const float* lstm_bih = (const float*)d_in[38];
  const float* lstm_bhh = (const float*)d_in[39];
  const float* time_emb = (const float*)d_in[40];
  const float* crit_w   = (const float*)d_in[41];
  const float* crit_b   = (const float*)d_in[42];
  const float* act_w    = (const float*)d_in[43];
  const float* act_b    = (const float*)d_in[44];

  float* ws = (float*)d_ws;
  float* gi    = ws + GI_OFF;
  float* hf    = ws + HF_OFF;
  float* hb    = ws + HB_OFF;
  float* x1    = ws + X1_OFF;
  float* x2    = ws + X2_OFF;
  float* ximg  = ws + XIMG_OFF;
  float* akin  = ws + AKIN_OFF;
  float* psum  = ws + PSUM_OFF;
  float* nsum  = ws + NSUM_OFF;
  float* gatev = ws + GATE_OFF;
  float* featv = ws + FEAT_OFF;
  float* gvec  = ws + G_OFF;

  float* out = (float*)d_out;

  gi_kernel      <<<160, 256, 0, stream>>>(emb, gru_wih, gru_bih, prev, curr, nxt, gi);
  gru_scan_kernel<<<6,   512, 0, stream>>>(gru_whh, gru_bhh, gi, hf, hb);
  conv1_kernel   <<<450, 256, 0, stream>>>(x, conv1_w, conv1_b, x1);
  conv2_kernel   <<<49,  256, 0, stream>>>(x1, conv2_w, conv2_b, x2);
  conv3_kernel   <<<9,   256, 0, stream>>>(x2, conv3_w, conv3_b, ximg);
  imgemb_kernel  <<<32,  256, 0, stream>>>(ximg, img_w, img_b, hf, hb, akin);
  attend_kernel  <<<2,   512, 0, stream>>>(akin, akp_w, akp_b, akn_w, akn_b,
                                           bil_p_w, bil_p_b, bil_n_w, bil_n_b,
                                           hf, hb, psum, nsum);
  head_a_kernel  <<<1,   256, 0, stream>>>(psum, nsum, akin,
                                           pred_w, pred_b, nred_w, nred_b,
                                           gate_w, gate_b, gatev);
  lin_kernel     <<<32,  256, 0, stream>>>(ximg, gatev, lin_w, lin_b, featv);
  lstm_kernel    <<<4,   256, 0, stream>>>(featv, hx, lstm_wih, lstm_whh,
                                           lstm_bih, lstm_bhh, gvec);
  final_kernel   <<<1,   320, 0, stream>>>(gvec, cx, tx, time_emb,
                                           crit_w, crit_b, act_w, act_b, out);
}